// Round 22
// baseline (851.948 us; speedup 1.0000x reference)
//
#include <hip/hip_runtime.h>
#include <stdint.h>
#include <math.h>

// RNN predictor: B=2048, T=1024 teacher + FUT=64 AR, H=128.
// Round-22: BARRIER-FREE. One wave = one block = 2 samples; the entire
// recurrence lives in a single wave, so LDS write->read ordering comes from
// the wave's in-order instruction stream + in-order DS pipe (R1-proven).
// No __syncthreads anywhere in the loops; SINGLE h buffer (reads precede
// writes in program order each step).
//  - wave owns all 128 cols: 8 j-tiles x 4 kt = 32 S-MFMA + 4 o-MFMA.
//  - samples at A-rows {0,4} (sample s -> C-(g=s, reg 0), R17-verified).
//  - pi-layout byte(k) = (k&15)*16 + 2*(k>>4): lane (g<2,l15)'s 8 h'-values
//    (sample g, cols 16q+l15) = 16 contiguous bytes -> ONE ds_write_b128.
//  - A-read: 4x ds_read_b128 from lanes l15 in {0,4} (hbuf rows 0,1).
//  - o via piggyback MFMA (Wo col 0): lanes 0/16 hold o(sample 0/1);
//    AR feedback = one __shfl. o ring in LDS, flushed every 64 steps.
//  - grid 1024 x 64 thr -> 4 independent chains/CU (~1/SIMD), no barrier,
//    no phase-locking: wall = single-chain step latency.

#define TLEN  1024
#define FUT   64
#define HID   128
#define SPB   2
#define NT    64
#define NSTEP (TLEN + FUT)

typedef float f32x4 __attribute__((ext_vector_type(4)));
typedef _Float16 f16x8 __attribute__((ext_vector_type(8)));
typedef uint32_t u32x4 __attribute__((ext_vector_type(4)));

__device__ __forceinline__ f16x8 asf16(u32x4 v) {
    return __builtin_bit_cast(f16x8, v);
}
__device__ __forceinline__ float fast_tanh(float v) {
    return 1.0f - 2.0f / (__expf(2.0f * v) + 1.0f);   // saturates correctly
}
__device__ __forceinline__ uint32_t packh(float a, float b) {
    return (uint32_t)__builtin_bit_cast(unsigned short, (_Float16)a)
         | ((uint32_t)__builtin_bit_cast(unsigned short, (_Float16)b) << 16);
}

__global__ __launch_bounds__(NT, 1) void rnn_kernel(
    const float* __restrict__ x,      // [B, T]
    const float* __restrict__ W_ih,   // [H, 1]
    const float* __restrict__ W_hh,   // [H, H]
    const float* __restrict__ b_ih,   // [H]
    const float* __restrict__ b_hh,   // [H]
    const float* __restrict__ W_out,  // [1, H]
    const float* __restrict__ b_out,  // [1]
    float* __restrict__ out)          // [B, T+FUT]
{
    // h: [row s=0..1][pi(k)] fp16, row 256B. SINGLE buffer (in-wave order).
    __shared__ __align__(16) unsigned short hbuf[SPB * HID];   // 512B
    __shared__ __align__(16) float xstg[SPB][128];             // 1KB
    __shared__ __align__(16) float ring[2][SPB][68];           // o ring

    const int lane = threadIdx.x & 63;
    const int l15  = lane & 15;
    const int g    = lane >> 4;
    const int s0   = blockIdx.x * SPB;

    // ---- weight B-fragments, single fp16; slot(kt,g,e) -> k=16e+4kt+g ----
    f16x8 W_[8][4], Wo[4];            // W_[q][kt], col j_q = 16q + l15
    float bias[8], wih[8];
    #pragma unroll
    for (int q = 0; q < 8; ++q) {
        const int j = 16 * q + l15;
        const float* r0 = W_hh + (size_t)j * HID;
        #pragma unroll
        for (int kt = 0; kt < 4; ++kt) {
            #pragma unroll
            for (int e = 0; e < 8; ++e)
                W_[q][kt][e] = (_Float16)r0[16 * e + 4 * kt + g];
        }
        bias[q] = b_ih[j] + b_hh[j];
        wih[q]  = W_ih[j];
    }
    #pragma unroll
    for (int kt = 0; kt < 4; ++kt)
        #pragma unroll
        for (int e = 0; e < 8; ++e)
            Wo[kt][e] = (l15 == 0) ? (_Float16)W_out[16 * e + 4 * kt + g]
                                   : (_Float16)0.0f;
    const float bo = b_out[0];

    // ---- LDS byte offsets (no swizzle; audited: reads 2-way, writes 4-way
    //      minimum-bandwidth for their sizes) ----
    const int s_ = l15 >> 2;          // A-read row, active lanes l15 in {0,4}
    int aoff[4];
    #pragma unroll
    for (int kt = 0; kt < 4; ++kt)
        aoff[kt] = s_ * 256 + (4 * kt + g) * 16;
    const int woff = g * 256 + l15 * 16;   // h'-write, lanes g<SPB, 16B

    // zero h (one wave: 128 u32 over 64 lanes)
    #pragma unroll
    for (int it = 0; it < 2; ++it)
        ((uint32_t*)hbuf)[it * NT + lane] = 0;

    u32x4 A_[4];
    #pragma unroll
    for (int kt = 0; kt < 4; ++kt) A_[kt] = (u32x4){0, 0, 0, 0};

    // ================= teacher-forced loop =================
    for (int i = 0; i < TLEN; ++i) {
        if ((i & 127) == 0) {         // refill x: 2 samples x 128 t
            const int s = lane >> 5, t0 = (lane & 31) * 4;
            const f32x4 xv = *(const f32x4*)&x[(size_t)(s0 + s) * TLEN + i + t0];
            *(f32x4*)&xstg[s][t0] = xv;
        }
        if (i > 64 && (i & 63) == 1 && lane < 32) {   // flush o ring
            const int q = ((i - 65) >> 6) & 1;
            const int s = lane >> 4, c4 = (lane & 15) * 4;
            const f32x4 v = *(const f32x4*)&ring[q][s][c4];
            *(f32x4*)&out[(size_t)(s0 + s) * NSTEP + (i - 65) + c4] = v;
        }

        // A-fragments of h_i (reads precede this step's writes)
        if (l15 < 8 && (l15 & 3) == 0) {
            #pragma unroll
            for (int kt = 0; kt < 4; ++kt)
                A_[kt] = *(const u32x4*)((const char*)hbuf + aoff[kt]);
        }

        // 36 MFMA: 8 S-tile chains + 1 o chain
        f32x4 sv[8], ov = {0.f, 0.f, 0.f, 0.f};
        #pragma unroll
        for (int q = 0; q < 8; ++q) sv[q] = (f32x4){0.f, 0.f, 0.f, 0.f};
        #pragma unroll
        for (int kt = 0; kt < 4; ++kt) {
            #pragma unroll
            for (int q = 0; q < 8; ++q)
                sv[q] = __builtin_amdgcn_mfma_f32_16x16x32_f16(asf16(A_[kt]), W_[q][kt], sv[q], 0, 0, 0);
            ov = __builtin_amdgcn_mfma_f32_16x16x32_f16(asf16(A_[kt]), Wo[kt], ov, 0, 0, 0);
        }

        // o_{i-1}[sample g] at lanes (g<SPB, l15==0)
        if (i > 0 && l15 == 0 && g < SPB)
            ring[((i - 1) >> 6) & 1][g][(i - 1) & 63] = ov[0] + bo;

        // epilogue: sample g (C reg 0), 8 cols 16q+l15; one b128 write
        const float in = xstg[g & 1][i & 127];
        float hv[8];
        #pragma unroll
        for (int q = 0; q < 8; ++q)
            hv[q] = fast_tanh(sv[q][0] + bias[q] + in * wih[q]);
        if (g < SPB) {
            u32x4 pk;
            pk[0] = packh(hv[0], hv[1]);
            pk[1] = packh(hv[2], hv[3]);
            pk[2] = packh(hv[4], hv[5]);
            pk[3] = packh(hv[6], hv[7]);
            *(u32x4*)((char*)hbuf + woff) = pk;
        }
    }

    // ================= autoregressive loop =================
    for (int i = TLEN; i < NSTEP; ++i) {
        if ((i & 63) == 1 && lane < 32) {   // flush (fires at i=1025)
            const int q = ((i - 65) >> 6) & 1;
            const int s = lane >> 4, c4 = (lane & 15) * 4;
            const f32x4 v = *(const f32x4*)&ring[q][s][c4];
            *(f32x4*)&out[(size_t)(s0 + s) * NSTEP + (i - 65) + c4] = v;
        }

        if (l15 < 8 && (l15 & 3) == 0) {
            #pragma unroll
            for (int kt = 0; kt < 4; ++kt)
                A_[kt] = *(const u32x4*)((const char*)hbuf + aoff[kt]);
        }

        f32x4 sv[8], ov = {0.f, 0.f, 0.f, 0.f};
        #pragma unroll
        for (int q = 0; q < 8; ++q) sv[q] = (f32x4){0.f, 0.f, 0.f, 0.f};
        #pragma unroll
        for (int kt = 0; kt < 4; ++kt) {
            #pragma unroll
            for (int q = 0; q < 8; ++q)
                sv[q] = __builtin_amdgcn_mfma_f32_16x16x32_f16(asf16(A_[kt]), W_[q][kt], sv[q], 0, 0, 0);
            ov = __builtin_amdgcn_mfma_f32_16x16x32_f16(asf16(A_[kt]), Wo[kt], ov, 0, 0, 0);
        }
        const float oval = ov[0] + bo;      // sample g at lanes 0 / 16
        if (l15 == 0 && g < SPB)
            ring[((i - 1) >> 6) & 1][g][(i - 1) & 63] = oval;

        const float in = __shfl(oval, (g & 1) << 4);   // feedback
        float hv[8];
        #pragma unroll
        for (int q = 0; q < 8; ++q)
            hv[q] = fast_tanh(sv[q][0] + bias[q] + in * wih[q]);
        if (g < SPB) {
            u32x4 pk;
            pk[0] = packh(hv[0], hv[1]);
            pk[1] = packh(hv[2], hv[3]);
            pk[2] = packh(hv[4], hv[5]);
            pk[3] = packh(hv[6], hv[7]);
            *(u32x4*)((char*)hbuf + woff) = pk;
        }
    }

    // tail: o_{NSTEP-1} = wout . h_{NSTEP}
    {
        if (l15 < 8 && (l15 & 3) == 0) {
            #pragma unroll
            for (int kt = 0; kt < 4; ++kt)
                A_[kt] = *(const u32x4*)((const char*)hbuf + aoff[kt]);
        }
        f32x4 ov = {0.f, 0.f, 0.f, 0.f};
        #pragma unroll
        for (int kt = 0; kt < 4; ++kt)
            ov = __builtin_amdgcn_mfma_f32_16x16x32_f16(asf16(A_[kt]), Wo[kt], ov, 0, 0, 0);
        if (l15 == 0 && g < SPB)
            ring[0][g][63] = ov[0] + bo;    // (1087>>6)&1 = 0
    }
    // flush t = 1024..1087 (ring parity 0)
    if (lane < 32) {
        const int s = lane >> 4, c4 = (lane & 15) * 4;
        const f32x4 v = *(const f32x4*)&ring[0][s][c4];
        *(f32x4*)&out[(size_t)(s0 + s) * NSTEP + TLEN + c4] = v;
    }
}

extern "C" void kernel_launch(void* const* d_in, const int* in_sizes, int n_in,
                              void* d_out, int out_size, void* d_ws, size_t ws_size,
                              hipStream_t stream) {
    const float* x     = (const float*)d_in[0];
    const float* W_ih  = (const float*)d_in[1];
    const float* W_hh  = (const float*)d_in[2];
    const float* b_ih  = (const float*)d_in[3];
    const float* b_hh  = (const float*)d_in[4];
    const float* W_out = (const float*)d_in[5];
    const float* b_out = (const float*)d_in[6];
    float* out = (float*)d_out;

    dim3 grid(2048 / SPB);   // 1024 single-wave blocks -> 4 chains/CU
    dim3 block(NT);
    rnn_kernel<<<grid, block, 0, stream>>>(x, W_ih, W_hh, b_ih, b_hh,
                                           W_out, b_out, out);
}